// Round 13
// baseline (3990.595 us; speedup 1.0000x reference)
//
#include <hip/hip_runtime.h>
#include <cstdint>
#include <cstddef>

// ============================================================================
// Persistent fused 2-layer LSTM + FC for MI355X (gfx950) — Round 18:
// L0 FINE-GRAINED CHUNK DATAFLOW. R17 showed T = T_L0 = 4.56us/step (L1 fix
// gave only -4% => L0 binds). L0's old loop serialized [wait max-over-32
// tags][stage 32KB][compute][finalize] with 3 barriers. Now: LDS chunk kc
// (32 units) comes from exactly one producer block (rho==kc), so wave w owns
// chunks 4w..4w+3: polls each tag individually, stages 1KB on arrival, sets
// an LDS flag. Compute consumes chunks in order via grouped LDS-flag spins
// (8 at a time) — MFMA on arrived chunks overlaps waiting for stragglers.
// x-part MFMAs run first with DIRECT global x frag loads (L1/L2-resident;
// ldsX + its barrier deleted). Barriers 3 -> 1 (end barrier = LDS-reuse
// guard + record-drain before tid0 tag). Poller count per tag line
// unchanged (32, same-address coalesced) — no R8/R14 storm class.
// "memory" fences pin dependent loads after poll exits (hoist hazard).
// L1 (R17 shortened-cycle version) and FC byte-identical to R17.
// ============================================================================

#define NTHR 512

typedef _Float16 f16;
typedef _Float16 f16x8 __attribute__((ext_vector_type(8)));
typedef float f32x4 __attribute__((ext_vector_type(4)));
typedef unsigned long long u64;

namespace {
constexpr int kT = 512, kI = 256, kH = 1024, kO = 512, kTR = 500;
constexpr int kSteps = 500;
constexpr size_t kHalfSlot = 32768;              // 16 b x 1024 u x f16
constexpr size_t kTagL0 = 0;
constexpr size_t kTagL1 = 4096;
constexpr size_t kH1Off = 16384;                 // [t][half][b:16][u:1024] f16
constexpr size_t kH2Off = kH1Off + 503ull * 2 * kHalfSlot;
// LDS geometry: 16B-aligned row pitch (2096B = 131x16), stride_dw 524==12
// mod 32 -> 2-way bank starts (free class).
constexpr int kRowH = 1048;
constexpr int kLdsBytes = 2 * 16 * kRowH * 2 + 4 * 16 * 17 * 4;  // 71424
}

__device__ __forceinline__ unsigned ld_tag(const void* p) {
  return __hip_atomic_load((const unsigned*)p, __ATOMIC_RELAXED,
                           __HIP_MEMORY_SCOPE_AGENT);
}
__device__ __forceinline__ void st_tag(void* p, unsigned v) {
  __hip_atomic_store((unsigned*)p, v, __ATOMIC_RELAXED,
                     __HIP_MEMORY_SCOPE_AGENT);
}
__device__ __forceinline__ void st_rec_u64(void* p, u64 v) {
  __hip_atomic_store((u64*)p, v, __ATOMIC_RELAXED, __HIP_MEMORY_SCOPE_AGENT);
}
__device__ __forceinline__ float sigmoid_f(float x) {
  return __builtin_amdgcn_rcpf(1.f + __expf(-x));
}
__device__ __forceinline__ float tanh_f(float x) {
  return 1.f - 2.f * __builtin_amdgcn_rcpf(1.f + __expf(2.f * x));
}
__device__ __forceinline__ f16x8 load8(const float* p) {
  f16x8 r;
#pragma unroll
  for (int j = 0; j < 8; ++j) r[j] = (f16)p[j];
  return r;
}
// pack 4 per-lane f16 h-values (lanes lg=0..3 over the same b) into one u64
__device__ __forceinline__ u64 pack4(float h, int lg) {
  f16 hv = (f16)h;
  unsigned short us;
  __builtin_memcpy(&us, &hv, 2);
  unsigned own = us;
  unsigned o1 = __shfl_xor((int)own, 16);
  unsigned p32 = (lg & 1) ? ((o1 & 0xffffu) | (own << 16))
                          : ((own & 0xffffu) | (o1 << 16));
  unsigned o2 = (unsigned)__shfl_xor((int)p32, 32);
  return (lg & 2) ? ((u64)o2 | ((u64)p32 << 32))
                  : ((u64)p32 | ((u64)o2 << 32));
}

__global__ void __launch_bounds__(256, 1) lstm_init_kernel(char* ws) {
  const int gid = blockIdx.x * 256 + threadIdx.x;   // 32768 threads
  unsigned* f = (unsigned*)ws;
  if (gid < 4096) f[gid] = 0u;                      // all tag regions
  u64* r1 = (u64*)(ws + kH1Off);                    // slot 0, both halves
  u64* r2 = (u64*)(ws + kH2Off);
  if (gid < 8192) { r1[gid] = 0ull; r2[gid] = 0ull; }
}

__global__ void __launch_bounds__(NTHR, 1) __attribute__((amdgpu_waves_per_eu(2)))
lstm_pipe_kernel(const float* __restrict__ x,
                 const float* __restrict__ Wih0, const float* __restrict__ Whh0,
                 const float* __restrict__ bih0, const float* __restrict__ bhh0,
                 const float* __restrict__ Wih1, const float* __restrict__ Whh1,
                 const float* __restrict__ bih1, const float* __restrict__ bhh1,
                 const float* __restrict__ Wfc, const float* __restrict__ bfc,
                 float* __restrict__ out, char* __restrict__ ws) {
  const int tid = threadIdx.x;
  const int bk = blockIdx.x;
  const int w = tid >> 6;
  const int lane = tid & 63;
  const int m = lane & 15;                  // A row idx / B col (=batch) / D col
  const int kg = lane >> 4;                 // k-group for A/B frags
  const int lg = lane >> 4;                 // D row group
  const int c = bk & 7, rho = bk >> 3;
  extern __shared__ char smem[];

  if (c < 2) {
    // ========== L0: h1 recurrence, scope 32, fine-grained chunks ===========
    const int half = c;
    const int q = m >> 2, g = m & 3;
    const int uA = rho * 32 + 4 * w + q;    // A-row unit
    const int uD = rho * 32 + 4 * w + lg;   // D-row unit (gate math/store)
    f16x8 whh[32], wih[8];
#pragma unroll
    for (int kc = 0; kc < 32; ++kc)
      whh[kc] = load8(Whh0 + (size_t)(g * kH + uA) * kH + kc * 32 + kg * 8);
#pragma unroll
    for (int kx = 0; kx < 8; ++kx)
      wih[kx] = load8(Wih0 + (size_t)(g * kH + uA) * kI + kx * 32 + kg * 8);
    float bias[4];
#pragma unroll
    for (int j = 0; j < 4; ++j) bias[j] = bih0[j * kH + uD] + bhh0[j * kH + uD];
    float cst = 0.f;
    f16* ldsH = (f16*)smem;                              // [16][1048]
    unsigned* ldsFlag = (unsigned*)(smem + 16 * kRowH * 2);  // [32] dwords
    unsigned* tagMy = (unsigned*)(ws + kTagL0 + (size_t)half * 2048);
    const int sb2 = lane >> 2, pc = lane & 3;            // chunk-stage lanes

    if (tid < 32) ldsFlag[tid] = 0u;
    __syncthreads();

    for (int t = 1; t <= kSteps; ++t) {
      // ---- x-part first (tag-independent): direct global frag loads
      f32x4 acc = {0.f, 0.f, 0.f, 0.f};
      {
        const float* xrow = x + ((size_t)(half * 16 + m) * kT + (t - 1)) * kI;
#pragma unroll
        for (int kx = 0; kx < 8; ++kx) {
          f16x8 bf = load8(xrow + kx * 32 + kg * 8);
          acc = __builtin_amdgcn_mfma_f32_16x16x32_f16(wih[kx], bf, acc, 0, 0, 0);
        }
      }
      // ---- stage own 4 chunks (ch = 4w+j) as their tags arrive
      {
        const char* rec = ws + kH1Off + ((size_t)(t - 1) * 2 + half) * kHalfSlot;
        const unsigned tgt = (unsigned)(t - 1);
        for (int j = 0; j < 4; ++j) {
          const int ch = 4 * w + j;
          const unsigned* tp = tagMy + (size_t)ch * 16;
          while (ld_tag(tp) < tgt) __builtin_amdgcn_s_sleep(1);
          asm volatile("" ::: "memory");  // no load hoisting above poll
          f16x8 v = *(const f16x8*)(rec + (size_t)sb2 * 2048 + ch * 64 + pc * 16);
          *(f16x8*)(ldsH + sb2 * kRowH + ch * 32 + pc * 8) = v;
          asm volatile("s_waitcnt lgkmcnt(0)" ::: "memory");  // data in LDS
          if (lane == 0)
            __hip_atomic_store(&ldsFlag[ch], (unsigned)t, __ATOMIC_RELAXED,
                               __HIP_MEMORY_SCOPE_WORKGROUP);
        }
      }
      // ---- consume chunks in groups of 8 (flag spin amortized)
      {
        const unsigned tgt = (unsigned)t;
        for (int grp = 0; grp < 4; ++grp) {
          bool done;
          do {
            unsigned fv = __hip_atomic_load(&ldsFlag[grp * 8 + (lane & 7)],
                                            __ATOMIC_RELAXED,
                                            __HIP_MEMORY_SCOPE_WORKGROUP);
            done = __all((int)(fv >= tgt));
            if (!done) __builtin_amdgcn_s_sleep(1);
          } while (!done);
          asm volatile("" ::: "memory");  // pin ds_reads after spin
#pragma unroll
          for (int k2 = 0; k2 < 8; ++k2) {
            const int kc = grp * 8 + k2;
            f16x8 bf = *(const f16x8*)(ldsH + m * kRowH + kc * 32 + kg * 8);
            acc = __builtin_amdgcn_mfma_f32_16x16x32_f16(whh[kc], bf, acc, 0, 0, 0);
          }
        }
      }
      // ---- gates (lane holds 4 gates of unit uD, batch m)
      const float pi = acc[0] + bias[0], pf = acc[1] + bias[1];
      const float pg = acc[2] + bias[2], po = acc[3] + bias[3];
      cst = sigmoid_f(pf) * cst + sigmoid_f(pi) * tanh_f(pg);
      const float h = sigmoid_f(po) * tanh_f(cst);
      const u64 pk = pack4(h, lg);
      if (lane < 16) {                      // b = lane, units rho*32+4w..+3
        st_rec_u64(ws + kH1Off + ((size_t)t * 2 + half) * kHalfSlot +
                       (size_t)lane * 2048 + (size_t)(rho * 32 + 4 * w) * 2,
                   pk);
      }
      asm volatile("s_waitcnt vmcnt(0)" ::: "memory");  // record drained
      __syncthreads();                      // all drained + LDS reuse guard
      if (tid == 0) st_tag(tagMy + (size_t)rho * 16, (unsigned)t);
    }

  } else if (c < 6) {
    // ============ L1: h2 recurrence, scope 64, R17 shortened cycle =========
    const int half = c & 1;
    const int rank = rho + ((c >= 4) ? 32 : 0);   // 0..63
    const int u0 = rank * 16;
    const int rg = w & 3, kh = w >> 2;            // row-group / K-side
    const int q = m >> 2, g = m & 3;
    const int uA = u0 + 4 * rg + q;
    const int uD = u0 + 4 * rg + lg;
    const float* WA = kh ? Whh1 : Wih1;           // kh1 = h2 side, kh0 = h1
    f16x8 wa[32];
#pragma unroll
    for (int kc = 0; kc < 32; ++kc)
      wa[kc] = load8(WA + (size_t)(g * kH + uA) * kH + kc * 32 + kg * 8);
    float bias[4];                                 // used by kh0 (gate waves)
#pragma unroll
    for (int j = 0; j < 4; ++j) bias[j] = bih1[j * kH + uD] + bhh1[j * kH + uD];
    float cst = 0.f;                               // c-state lives on kh0
    f16* ldsH1 = (f16*)smem;                       // [16][1048] h1[t]
    f16* ldsH2 = (f16*)(smem + 16 * kRowH * 2);    // [16][1048] h2[t-1]
    float* zone = (float*)(smem + 2 * 16 * kRowH * 2);  // [4][16][17] h2-part
    unsigned* tagL0h = (unsigned*)(ws + kTagL0 + (size_t)half * 2048);
    unsigned* tagL1h = (unsigned*)(ws + kTagL1 + (size_t)half * 4096);
    const int sb = tid >> 7, so = (tid & 127) * 8;

    for (int t = 1; t <= kSteps; ++t) {
      // ---- phase 1: own-layer wait only (h2[t-1] tags)
      if (w == 7) {
        const unsigned tgtB = (unsigned)(t - 1);
        const unsigned* tpB = tagL1h + (size_t)lane * 16;
        bool done;
        do {
          done = __all((int)(ld_tag(tpB) >= tgtB));
          if (!done) __builtin_amdgcn_s_sleep(1);
        } while (!done);
      }
      __syncthreads();                      // B-tags observed
      // ---- phase 2: h2 -> regs; w7 polls h1 tags under load latency
      {
        const char* r2 = ws + kH2Off + ((size_t)(t - 1) * 2 + half) * kHalfSlot;
        f16x8 b0 = *(const f16x8*)(r2 + (size_t)tid * 16);
        f16x8 b1 = *(const f16x8*)(r2 + (size_t)(tid + 512) * 16);
        f16x8 b2 = *(const f16x8*)(r2 + (size_t)(tid + 1024) * 16);
        f16x8 b3 = *(const f16x8*)(r2 + (size_t)(tid + 1536) * 16);
        if (w == 7) {                       // h1[t] from L0 (usually ready)
          const unsigned tgtA = (unsigned)t;
          const unsigned* tpA = tagL0h + (size_t)(lane & 31) * 16;
          bool done;
          do {
            done = __all((int)(ld_tag(tpA) >= tgtA));
            if (!done) __builtin_amdgcn_s_sleep(1);
          } while (!done);
        }
        *(f16x8*)(ldsH2 + (sb + 0) * kRowH + so) = b0;
        *(f16x8*)(ldsH2 + (sb + 4) * kRowH + so) = b1;
        *(f16x8*)(ldsH2 + (sb + 8) * kRowH + so) = b2;
        *(f16x8*)(ldsH2 + (sb + 12) * kRowH + so) = b3;
      }
      __syncthreads();                      // LDS2 ready + A-tags observed
      // ---- phase 3: kh1 computes h2-side + zone; kh0 stages h1 32KB
      if (kh == 1) {
        f32x4 acc = {0.f, 0.f, 0.f, 0.f};
#pragma unroll
        for (int kc = 0; kc < 32; ++kc) {
          f16x8 bf = *(const f16x8*)(ldsH2 + m * kRowH + kc * 32 + kg * 8);
          acc = __builtin_amdgcn_mfma_f32_16x16x32_f16(wa[kc], bf, acc, 0, 0, 0);
        }
#pragma unroll
        for (int j = 0; j < 4; ++j)
          zone[(rg * 16 + lg * 4 + j) * 17 + m] = acc[j];
      } else {
        const char* r1 = ws + kH1Off + ((size_t)t * 2 + half) * kHalfSlot;
        f16x8 a[8];
#pragma unroll
        for (int j = 0; j < 8; ++j)
          a[j] = *(const f16x8*)(r1 + ((size_t)(j * 256 + tid)) * 16);
#pragma unroll
        for (int j = 0; j < 8; ++j) {
          const int i = j * 256 + tid;
          *(f16x8*)(ldsH1 + (i >> 7) * kRowH + (i & 127) * 8) = a[j];
        }
      }
      __syncthreads();                      // zone + LDS1 ready
      // ---- phase 4: kh0 h1-side MFMAs + combine + gates + store + drain
      if (kh == 0) {
        f32x4 acc = {0.f, 0.f, 0.f, 0.f};
#pragma unroll
        for (int kc = 0; kc < 32; ++kc) {
          f16x8 bf = *(const f16x8*)(ldsH1 + m * kRowH + kc * 32 + kg * 8);
          acc = __builtin_amdgcn_mfma_f32_16x16x32_f16(wa[kc], bf, acc, 0, 0, 0);
        }
        const float pi = acc[0] + zone[(rg * 16 + lg * 4 + 0) * 17 + m] + bias[0];
        const float pf = acc[1] + zone[(rg * 16 + lg * 4 + 1) * 17 + m] + bias[1];
        const float pg = acc[2] + zone[(rg * 16 + lg * 4 + 2) * 17 + m] + bias[2];
        const float po = acc[3] + zone[(rg * 16 + lg * 4 + 3) * 17 + m] + bias[3];
        cst = sigmoid_f(pf) * cst + sigmoid_f(pi) * tanh_f(pg);
        const float h = sigmoid_f(po) * tanh_f(cst);
        const u64 pk = pack4(h, lg);
        if (lane < 16) {
          st_rec_u64(ws + kH2Off + ((size_t)t * 2 + half) * kHalfSlot +
                         (size_t)lane * 2048 + (size_t)(u0 + 4 * rg) * 2,
                     pk);
          asm volatile("s_waitcnt vmcnt(0)" ::: "memory");
        }
      }
      __syncthreads();                      // kh0 records drained
      if (tid == 0) st_tag(tagL1h + (size_t)rank * 16, (unsigned)t);
    }

  } else {
    // ===================== FC: out = Wfc @ h2[t] + b =======================
    const int half = c - 6;
    const int o0 = rho * 16;
    f16x8 wf[4];
#pragma unroll
    for (int i = 0; i < 4; ++i)
      wf[i] = load8(Wfc + (size_t)(o0 + m) * kH + (size_t)(w + 8 * i) * 32 + kg * 8);
    f16* ldsH = (f16*)smem;                        // [16][1048] h2[t]
    float* zone = (float*)(smem + 16 * kRowH * 2); // [8][16][17] per-wave
    unsigned* tagL1h = (unsigned*)(ws + kTagL1 + (size_t)half * 4096);
    const int sb = tid >> 7, so = (tid & 127) * 8;
    const int ob = lane >> 2, op = lane & 3;
    float4 bf4;
    if (w == 0) bf4 = *(const float4*)(bfc + o0 + op * 4);

    for (int t = 1; t <= kSteps; ++t) {
      if (w == 7) {
        const unsigned tgt = (unsigned)t;
        const unsigned* tp = tagL1h + (size_t)lane * 16;
        bool done;
        do {
          done = __all((int)(ld_tag(tp) >= tgt));
          if (!done) __builtin_amdgcn_s_sleep(1);
        } while (!done);
      }
      __syncthreads();
      {
        const char* r2 = ws + kH2Off + ((size_t)t * 2 + half) * kHalfSlot;
        f16x8 b0 = *(const f16x8*)(r2 + (size_t)tid * 16);
        f16x8 b1 = *(const f16x8*)(r2 + (size_t)(tid + 512) * 16);
        f16x8 b2 = *(const f16x8*)(r2 + (size_t)(tid + 1024) * 16);
        f16x8 b3 = *(const f16x8*)(r2 + (size_t)(tid + 1536) * 16);
        *(f16x8*)(ldsH + (sb + 0) * kRowH + so) = b0;
        *(f16x8*)(ldsH + (sb + 4) * kRowH + so) = b1;
        *(f16x8*)(ldsH + (sb + 8) * kRowH + so) = b2;
        *(f16x8*)(ldsH + (sb + 12) * kRowH + so) = b3;
      }
      __syncthreads();
      f32x4 acc = {0.f, 0.f, 0.f, 0.f};
#pragma unroll
      for (int i = 0; i < 4; ++i) {
        f16x8 bf = *(const f16x8*)(ldsH + m * kRowH + (w + 8 * i) * 32 + kg * 8);
        acc = __builtin_amdgcn_mfma_f32_16x16x32_f16(wf[i], bf, acc, 0, 0, 0);
      }
#pragma unroll
      for (int j = 0; j < 4; ++j)
        zone[(w * 16 + lg * 4 + j) * 17 + m] = acc[j];    // per-wave slice
      __syncthreads();
      if (w == 0) {                          // sum 8 slices, + bias, store
        float4 v;
#pragma unroll
        for (int jj = 0; jj < 4; ++jj) {
          float s = 0.f;
#pragma unroll
          for (int ww = 0; ww < 8; ++ww)
            s += zone[(ww * 16 + op * 4 + jj) * 17 + ob];
          ((float*)&v)[jj] = s + ((const float*)&bf4)[jj];
        }
        *(float4*)(out + ((size_t)(half * 16 + ob) * kTR + (t - 1)) * kO +
                   o0 + op * 4) = v;
      }
    }
  }
}

extern "C" void kernel_launch(void* const* d_in, const int* in_sizes, int n_in,
                              void* d_out, int out_size, void* d_ws,
                              size_t ws_size, hipStream_t stream) {
  const float* x    = (const float*)d_in[0];
  const float* Wih0 = (const float*)d_in[1];
  const float* Whh0 = (const float*)d_in[2];
  const float* bih0 = (const float*)d_in[3];
  const float* bhh0 = (const float*)d_in[4];
  const float* Wih1 = (const float*)d_in[5];
  const float* Whh1 = (const float*)d_in[6];
  const float* bih1 = (const float*)d_in[7];
  const float* bhh1 = (const float*)d_in[8];
  const float* Wfc  = (const float*)d_in[9];
  const float* bfc  = (const float*)d_in[10];
  float* out = (float*)d_out;
  char* ws   = (char*)d_ws;

  (void)hipFuncSetAttribute((const void*)lstm_pipe_kernel,
                            hipFuncAttributeMaxDynamicSharedMemorySize,
                            kLdsBytes);

  hipLaunchKernelGGL(lstm_init_kernel, dim3(128), dim3(256), 0, stream, ws);
  hipLaunchKernelGGL(lstm_pipe_kernel, dim3(256), dim3(NTHR), kLdsBytes,
                     stream, x, Wih0, Whh0, bih0, bhh0, Wih1, Whh1, bih1,
                     bhh1, Wfc, bfc, out, ws);
}

// Round 14
// 2624.804 us; speedup vs baseline: 1.5203x; 1.5203x over previous
//
#include <hip/hip_runtime.h>
#include <cstdint>
#include <cstddef>

// ============================================================================
// Persistent fused 2-layer LSTM + FC for MI355X (gfx950) — Round 19:
// R17 (2281us best) + COUNTER-BASED TAG POST. R18 post-mortem: serial
// per-chunk LLC polls doubled step time (poll parallelism across lanes is
// load-bearing) -> full revert to R17 structure. This round trims L0's tail:
// old: stores -> per-wave vmcnt -> FULL BARRIER -> tid0 tag (tag waits for
// slowest wave to converge at barrier + extra hop). New: after its vmcnt
// drain, each wave's lane0 does LDS atomicAdd; the 8th arrival posts the
// tag IMMEDIATELY (all drains happen-before 8th add). End barrier deleted;
// ldsX double-buffered by parity (barrier was its reuse guard); ldsH is
// guarded by next step's barrier1. Same trim in L1 phase 4 (4-wave counter).
// Counters are monotonic (target w*t) — no reset, no extra sync.
// Tag lines stay single-writer; poll shapes unchanged. FC unchanged.
// ============================================================================

#define NTHR 512

typedef _Float16 f16;
typedef _Float16 f16x8 __attribute__((ext_vector_type(8)));
typedef float f32x4 __attribute__((ext_vector_type(4)));
typedef unsigned long long u64;

namespace {
constexpr int kT = 512, kI = 256, kH = 1024, kO = 512, kTR = 500;
constexpr int kSteps = 500;
constexpr size_t kHalfSlot = 32768;              // 16 b x 1024 u x f16
constexpr size_t kTagL0 = 0;
constexpr size_t kTagL1 = 4096;
constexpr size_t kH1Off = 16384;                 // [t][half][b:16][u:1024] f16
constexpr size_t kH2Off = kH1Off + 503ull * 2 * kHalfSlot;
// LDS geometry: 16B-aligned row pitch (2096B = 131x16), stride_dw 524==12
// mod 32 -> 2-way bank starts (free class).
constexpr int kRowH = 1048;
constexpr int kRowX = 264;
constexpr int kHBytes = 16 * kRowH * 2;          // 33536
constexpr int kXBytes = 16 * kRowX * 2;          // 8448
// max across branches: L1 = 2*kHBytes + zone(4*16*17*4) + cnt(64) = 71488
constexpr int kLdsBytes = 2 * kHBytes + 4 * 16 * 17 * 4 + 64;
}

__device__ __forceinline__ unsigned ld_tag(const void* p) {
  return __hip_atomic_load((const unsigned*)p, __ATOMIC_RELAXED,
                           __HIP_MEMORY_SCOPE_AGENT);
}
__device__ __forceinline__ void st_tag(void* p, unsigned v) {
  __hip_atomic_store((unsigned*)p, v, __ATOMIC_RELAXED,
                     __HIP_MEMORY_SCOPE_AGENT);
}
__device__ __forceinline__ void st_rec_u64(void* p, u64 v) {
  __hip_atomic_store((u64*)p, v, __ATOMIC_RELAXED, __HIP_MEMORY_SCOPE_AGENT);
}
__device__ __forceinline__ float sigmoid_f(float x) {
  return __builtin_amdgcn_rcpf(1.f + __expf(-x));
}
__device__ __forceinline__ float tanh_f(float x) {
  return 1.f - 2.f * __builtin_amdgcn_rcpf(1.f + __expf(2.f * x));
}
__device__ __forceinline__ f16x8 load8(const float* p) {
  f16x8 r;
#pragma unroll
  for (int j = 0; j < 8; ++j) r[j] = (f16)p[j];
  return r;
}
// pack 4 per-lane f16 h-values (lanes lg=0..3 over the same b) into one u64
__device__ __forceinline__ u64 pack4(float h, int lg) {
  f16 hv = (f16)h;
  unsigned short us;
  __builtin_memcpy(&us, &hv, 2);
  unsigned own = us;
  unsigned o1 = __shfl_xor((int)own, 16);
  unsigned p32 = (lg & 1) ? ((o1 & 0xffffu) | (own << 16))
                          : ((own & 0xffffu) | (o1 << 16));
  unsigned o2 = (unsigned)__shfl_xor((int)p32, 32);
  return (lg & 2) ? ((u64)o2 | ((u64)p32 << 32))
                  : ((u64)p32 | ((u64)o2 << 32));
}

__global__ void __launch_bounds__(256, 1) lstm_init_kernel(char* ws) {
  const int gid = blockIdx.x * 256 + threadIdx.x;   // 32768 threads
  unsigned* f = (unsigned*)ws;
  if (gid < 4096) f[gid] = 0u;                      // all tag regions
  u64* r1 = (u64*)(ws + kH1Off);                    // slot 0, both halves
  u64* r2 = (u64*)(ws + kH2Off);
  if (gid < 8192) { r1[gid] = 0ull; r2[gid] = 0ull; }
}

__global__ void __launch_bounds__(NTHR, 1) __attribute__((amdgpu_waves_per_eu(2)))
lstm_pipe_kernel(const float* __restrict__ x,
                 const float* __restrict__ Wih0, const float* __restrict__ Whh0,
                 const float* __restrict__ bih0, const float* __restrict__ bhh0,
                 const float* __restrict__ Wih1, const float* __restrict__ Whh1,
                 const float* __restrict__ bih1, const float* __restrict__ bhh1,
                 const float* __restrict__ Wfc, const float* __restrict__ bfc,
                 float* __restrict__ out, char* __restrict__ ws) {
  const int tid = threadIdx.x;
  const int bk = blockIdx.x;
  const int w = tid >> 6;
  const int lane = tid & 63;
  const int m = lane & 15;                  // A row idx / B col (=batch) / D col
  const int kg = lane >> 4;                 // k-group for A/B frags
  const int lg = lane >> 4;                 // D row group
  const int c = bk & 7, rho = bk >> 3;
  extern __shared__ char smem[];

  if (c < 2) {
    // ===================== L0: h1 recurrence, scope 32 =====================
    const int half = c;
    const int q = m >> 2, g = m & 3;
    const int uA = rho * 32 + 4 * w + q;    // A-row unit
    const int uD = rho * 32 + 4 * w + lg;   // D-row unit (gate math/store)
    f16x8 whh[32], wih[8];
#pragma unroll
    for (int kc = 0; kc < 32; ++kc)
      whh[kc] = load8(Whh0 + (size_t)(g * kH + uA) * kH + kc * 32 + kg * 8);
#pragma unroll
    for (int kx = 0; kx < 8; ++kx)
      wih[kx] = load8(Wih0 + (size_t)(g * kH + uA) * kI + kx * 32 + kg * 8);
    float bias[4];
#pragma unroll
    for (int j = 0; j < 4; ++j) bias[j] = bih0[j * kH + uD] + bhh0[j * kH + uD];
    float cst = 0.f;
    f16* ldsH = (f16*)smem;                             // [16][1048]
    f16* ldsX0 = (f16*)(smem + kHBytes);                // x parity 0
    f16* ldsX1 = (f16*)(smem + kHBytes + kXBytes);      // x parity 1
    unsigned* cnt = (unsigned*)(smem + kHBytes + 2 * kXBytes);
    unsigned* tagMy = (unsigned*)(ws + kTagL0 + (size_t)half * 2048);
    const int xb = tid >> 5, xcol = (tid & 31) * 8;
    const int sb = tid >> 7, so = (tid & 127) * 8;      // h-stage LDS dest

    if (tid == 0) cnt[0] = 0u;
    __syncthreads();

    for (int t = 1; t <= kSteps; ++t) {
      if (w == 7) {                         // poll own cluster: h1[t-1] ready
        const unsigned tgt = (unsigned)(t - 1);
        const unsigned* tp = tagMy + (size_t)(lane & 31) * 16;
        bool done;
        do {
          done = __all((int)(ld_tag(tp) >= tgt));
          if (!done) __builtin_amdgcn_s_sleep(1);
        } while (!done);
      }
      {                                     // x slice -> LDS parity buffer
        f16* ldsX = (t & 1) ? ldsX1 : ldsX0;
        f16x8 xv = load8(x + ((size_t)(half * 16 + xb) * kT + (t - 1)) * kI + xcol);
        *(f16x8*)(ldsX + xb * kRowX + xcol) = xv;
      }
      __syncthreads();                      // B1: tags observed, x(t) ready
      {                                     // stage h1[t-1] 32KB -> LDS
        const char* rec = ws + kH1Off + ((size_t)(t - 1) * 2 + half) * kHalfSlot;
        f16x8 h0 = *(const f16x8*)(rec + (size_t)tid * 16);
        f16x8 h1v = *(const f16x8*)(rec + (size_t)(tid + 512) * 16);
        f16x8 h2v = *(const f16x8*)(rec + (size_t)(tid + 1024) * 16);
        f16x8 h3v = *(const f16x8*)(rec + (size_t)(tid + 1536) * 16);
        *(f16x8*)(ldsH + (sb + 0) * kRowH + so) = h0;
        *(f16x8*)(ldsH + (sb + 4) * kRowH + so) = h1v;
        *(f16x8*)(ldsH + (sb + 8) * kRowH + so) = h2v;
        *(f16x8*)(ldsH + (sb + 12) * kRowH + so) = h3v;
      }
      __syncthreads();                      // B2: stage complete
      f32x4 acc = {0.f, 0.f, 0.f, 0.f};
#pragma unroll
      for (int kc = 0; kc < 32; ++kc) {
        f16x8 bf = *(const f16x8*)(ldsH + m * kRowH + kc * 32 + kg * 8);
        acc = __builtin_amdgcn_mfma_f32_16x16x32_f16(whh[kc], bf, acc, 0, 0, 0);
      }
      {
        const f16* ldsX = (t & 1) ? ldsX1 : ldsX0;
#pragma unroll
        for (int kx = 0; kx < 8; ++kx) {
          f16x8 bf = *(const f16x8*)(ldsX + m * kRowX + kx * 32 + kg * 8);
          acc = __builtin_amdgcn_mfma_f32_16x16x32_f16(wih[kx], bf, acc, 0, 0, 0);
        }
      }
      // gates (lane holds 4 gates of unit uD, batch m)
      const float pi = acc[0] + bias[0], pf = acc[1] + bias[1];
      const float pg = acc[2] + bias[2], po = acc[3] + bias[3];
      cst = sigmoid_f(pf) * cst + sigmoid_f(pi) * tanh_f(pg);
      const float h = sigmoid_f(po) * tanh_f(cst);
      const u64 pk = pack4(h, lg);
      if (lane < 16) {                      // b = lane, units rho*32+4w..+3
        st_rec_u64(ws + kH1Off + ((size_t)t * 2 + half) * kHalfSlot +
                       (size_t)lane * 2048 + (size_t)(rho * 32 + 4 * w) * 2,
                   pk);
      }
      asm volatile("s_waitcnt vmcnt(0)" ::: "memory");  // records at LLC
      if (lane == 0) {                      // 8th wave posts the tag
        unsigned old = __hip_atomic_fetch_add(cnt, 1u, __ATOMIC_RELAXED,
                                              __HIP_MEMORY_SCOPE_WORKGROUP);
        if (old == 8u * (unsigned)t - 1u)
          st_tag(tagMy + (size_t)rho * 16, (unsigned)t);
      }
      // no end barrier: ldsH guarded by next B1; ldsX by parity.
    }

  } else if (c < 6) {
    // ============ L1: h2 recurrence, scope 64, R17 shortened cycle =========
    const int half = c & 1;
    const int rank = rho + ((c >= 4) ? 32 : 0);   // 0..63
    const int u0 = rank * 16;
    const int rg = w & 3, kh = w >> 2;            // row-group / K-side
    const int q = m >> 2, g = m & 3;
    const int uA = u0 + 4 * rg + q;
    const int uD = u0 + 4 * rg + lg;
    const float* WA = kh ? Whh1 : Wih1;           // kh1 = h2 side, kh0 = h1
    f16x8 wa[32];
#pragma unroll
    for (int kc = 0; kc < 32; ++kc)
      wa[kc] = load8(WA + (size_t)(g * kH + uA) * kH + kc * 32 + kg * 8);
    float bias[4];                                 // used by kh0 (gate waves)
#pragma unroll
    for (int j = 0; j < 4; ++j) bias[j] = bih1[j * kH + uD] + bhh1[j * kH + uD];
    float cst = 0.f;                               // c-state lives on kh0
    f16* ldsH1 = (f16*)smem;                       // [16][1048] h1[t]
    f16* ldsH2 = (f16*)(smem + kHBytes);           // [16][1048] h2[t-1]
    float* zone = (float*)(smem + 2 * kHBytes);    // [4][16][17] h2-part
    unsigned* cnt = (unsigned*)(smem + 2 * kHBytes + 4 * 16 * 17 * 4);
    unsigned* tagL0h = (unsigned*)(ws + kTagL0 + (size_t)half * 2048);
    unsigned* tagL1h = (unsigned*)(ws + kTagL1 + (size_t)half * 4096);
    const int sb = tid >> 7, so = (tid & 127) * 8;

    if (tid == 0) cnt[0] = 0u;
    __syncthreads();

    for (int t = 1; t <= kSteps; ++t) {
      // ---- phase 1: own-layer wait only (h2[t-1] tags)
      if (w == 7) {
        const unsigned tgtB = (unsigned)(t - 1);
        const unsigned* tpB = tagL1h + (size_t)lane * 16;
        bool done;
        do {
          done = __all((int)(ld_tag(tpB) >= tgtB));
          if (!done) __builtin_amdgcn_s_sleep(1);
        } while (!done);
      }
      __syncthreads();                      // B-tags observed
      // ---- phase 2: h2 -> regs; w7 polls h1 tags under load latency
      {
        const char* r2 = ws + kH2Off + ((size_t)(t - 1) * 2 + half) * kHalfSlot;
        f16x8 b0 = *(const f16x8*)(r2 + (size_t)tid * 16);
        f16x8 b1 = *(const f16x8*)(r2 + (size_t)(tid + 512) * 16);
        f16x8 b2 = *(const f16x8*)(r2 + (size_t)(tid + 1024) * 16);
        f16x8 b3 = *(const f16x8*)(r2 + (size_t)(tid + 1536) * 16);
        if (w == 7) {                       // h1[t] from L0 (usually ready)
          const unsigned tgtA = (unsigned)t;
          const unsigned* tpA = tagL0h + (size_t)(lane & 31) * 16;
          bool done;
          do {
            done = __all((int)(ld_tag(tpA) >= tgtA));
            if (!done) __builtin_amdgcn_s_sleep(1);
          } while (!done);
        }
        *(f16x8*)(ldsH2 + (sb + 0) * kRowH + so) = b0;
        *(f16x8*)(ldsH2 + (sb + 4) * kRowH + so) = b1;
        *(f16x8*)(ldsH2 + (sb + 8) * kRowH + so) = b2;
        *(f16x8*)(ldsH2 + (sb + 12) * kRowH + so) = b3;
      }
      __syncthreads();                      // LDS2 ready + A-tags observed
      // ---- phase 3: kh1 computes h2-side + zone; kh0 stages h1 32KB
      if (kh == 1) {
        f32x4 acc = {0.f, 0.f, 0.f, 0.f};
#pragma unroll
        for (int kc = 0; kc < 32; ++kc) {
          f16x8 bf = *(const f16x8*)(ldsH2 + m * kRowH + kc * 32 + kg * 8);
          acc = __builtin_amdgcn_mfma_f32_16x16x32_f16(wa[kc], bf, acc, 0, 0, 0);
        }
#pragma unroll
        for (int j = 0; j < 4; ++j)
          zone[(rg * 16 + lg * 4 + j) * 17 + m] = acc[j];
      } else {
        const char* r1 = ws + kH1Off + ((size_t)t * 2 + half) * kHalfSlot;
        f16x8 a[8];
#pragma unroll
        for (int j = 0; j < 8; ++j)
          a[j] = *(const f16x8*)(r1 + ((size_t)(j * 256 + tid)) * 16);
#pragma unroll
        for (int j = 0; j < 8; ++j) {
          const int i = j * 256 + tid;
          *(f16x8*)(ldsH1 + (i >> 7) * kRowH + (i & 127) * 8) = a[j];
        }
      }
      __syncthreads();                      // zone + LDS1 ready
      // ---- phase 4: kh0 h1-side MFMAs + combine + gates + store + drain;
      //      counter-post (4 kh0 waves), NO end barrier.
      if (kh == 0) {
        f32x4 acc = {0.f, 0.f, 0.f, 0.f};
#pragma unroll
        for (int kc = 0; kc < 32; ++kc) {
          f16x8 bf = *(const f16x8*)(ldsH1 + m * kRowH + kc * 32 + kg * 8);
          acc = __builtin_amdgcn_mfma_f32_16x16x32_f16(wa[kc], bf, acc, 0, 0, 0);
        }
        const float pi = acc[0] + zone[(rg * 16 + lg * 4 + 0) * 17 + m] + bias[0];
        const float pf = acc[1] + zone[(rg * 16 + lg * 4 + 1) * 17 + m] + bias[1];
        const float pg = acc[2] + zone[(rg * 16 + lg * 4 + 2) * 17 + m] + bias[2];
        const float po = acc[3] + zone[(rg * 16 + lg * 4 + 3) * 17 + m] + bias[3];
        cst = sigmoid_f(pf) * cst + sigmoid_f(pi) * tanh_f(pg);
        const float h = sigmoid_f(po) * tanh_f(cst);
        const u64 pk = pack4(h, lg);
        if (lane < 16) {
          st_rec_u64(ws + kH2Off + ((size_t)t * 2 + half) * kHalfSlot +
                         (size_t)lane * 2048 + (size_t)(u0 + 4 * rg) * 2,
                     pk);
        }
        asm volatile("s_waitcnt vmcnt(0)" ::: "memory");
        if (lane == 0) {
          unsigned old = __hip_atomic_fetch_add(cnt, 1u, __ATOMIC_RELAXED,
                                                __HIP_MEMORY_SCOPE_WORKGROUP);
          if (old == 4u * (unsigned)t - 1u)
            st_tag(tagL1h + (size_t)rank * 16, (unsigned)t);
        }
      }
      // no end barrier: LDS guarded by next phase-1/2 barriers.
    }

  } else {
    // ===================== FC: out = Wfc @ h2[t] + b =======================
    const int half = c - 6;
    const int o0 = rho * 16;
    f16x8 wf[4];
#pragma unroll
    for (int i = 0; i < 4; ++i)
      wf[i] = load8(Wfc + (size_t)(o0 + m) * kH + (size_t)(w + 8 * i) * 32 + kg * 8);
    f16* ldsH = (f16*)smem;                        // [16][1048] h2[t]
    float* zone = (float*)(smem + kHBytes);        // [8][16][17] per-wave
    unsigned* tagL1h = (unsigned*)(ws + kTagL1 + (size_t)half * 4096);
    const int sb = tid >> 7, so = (tid & 127) * 8;
    const int ob = lane >> 2, op = lane & 3;
    float4 bf4;
    if (w == 0) bf4 = *(const float4*)(bfc + o0 + op * 4);

    for (int t = 1; t <= kSteps; ++t) {
      if (w == 7) {
        const unsigned tgt = (unsigned)t;
        const unsigned* tp = tagL1h + (size_t)lane * 16;
        bool done;
        do {
          done = __all((int)(ld_tag(tp) >= tgt));
          if (!done) __builtin_amdgcn_s_sleep(1);
        } while (!done);
      }
      __syncthreads();
      {
        const char* r2 = ws + kH2Off + ((size_t)t * 2 + half) * kHalfSlot;
        f16x8 b0 = *(const f16x8*)(r2 + (size_t)tid * 16);
        f16x8 b1 = *(const f16x8*)(r2 + (size_t)(tid + 512) * 16);
        f16x8 b2 = *(const f16x8*)(r2 + (size_t)(tid + 1024) * 16);
        f16x8 b3 = *(const f16x8*)(r2 + (size_t)(tid + 1536) * 16);
        *(f16x8*)(ldsH + (sb + 0) * kRowH + so) = b0;
        *(f16x8*)(ldsH + (sb + 4) * kRowH + so) = b1;
        *(f16x8*)(ldsH + (sb + 8) * kRowH + so) = b2;
        *(f16x8*)(ldsH + (sb + 12) * kRowH + so) = b3;
      }
      __syncthreads();
      f32x4 acc = {0.f, 0.f, 0.f, 0.f};
#pragma unroll
      for (int i = 0; i < 4; ++i) {
        f16x8 bf = *(const f16x8*)(ldsH + m * kRowH + (w + 8 * i) * 32 + kg * 8);
        acc = __builtin_amdgcn_mfma_f32_16x16x32_f16(wf[i], bf, acc, 0, 0, 0);
      }
#pragma unroll
      for (int j = 0; j < 4; ++j)
        zone[(w * 16 + lg * 4 + j) * 17 + m] = acc[j];    // per-wave slice
      __syncthreads();
      if (w == 0) {                          // sum 8 slices, + bias, store
        float4 v;
#pragma unroll
        for (int jj = 0; jj < 4; ++jj) {
          float s = 0.f;
#pragma unroll
          for (int ww = 0; ww < 8; ++ww)
            s += zone[(ww * 16 + op * 4 + jj) * 17 + ob];
          ((float*)&v)[jj] = s + ((const float*)&bf4)[jj];
        }
        *(float4*)(out + ((size_t)(half * 16 + ob) * kTR + (t - 1)) * kO +
                   o0 + op * 4) = v;
      }
    }
  }
}

extern "C" void kernel_launch(void* const* d_in, const int* in_sizes, int n_in,
                              void* d_out, int out_size, void* d_ws,
                              size_t ws_size, hipStream_t stream) {
  const float* x    = (const float*)d_in[0];
  const float* Wih0 = (const float*)d_in[1];
  const float* Whh0 = (const float*)d_in[2];
  const float* bih0 = (const float*)d_in[3];
  const float* bhh0 = (const float*)d_in[4];
  const float* Wih1 = (const float*)d_in[5];
  const float* Whh1 = (const float*)d_in[6];
  const float* bih1 = (const float*)d_in[7];
  const float* bhh1 = (const float*)d_in[8];
  const float* Wfc  = (const float*)d_in[9];
  const float* bfc  = (const float*)d_in[10];
  float* out = (float*)d_out;
  char* ws   = (char*)d_ws;

  (void)hipFuncSetAttribute((const void*)lstm_pipe_kernel,
                            hipFuncAttributeMaxDynamicSharedMemorySize,
                            kLdsBytes);

  hipLaunchKernelGGL(lstm_init_kernel, dim3(128), dim3(256), 0, stream, ws);
  hipLaunchKernelGGL(lstm_pipe_kernel, dim3(256), dim3(NTHR), kLdsBytes,
                     stream, x, Wih0, Whh0, bih0, bhh0, Wih1, Whh1, bih1,
                     bhh1, Wfc, bfc, out, ws);
}